// Round 1
// baseline (688.952 us; speedup 1.0000x reference)
//
#include <hip/hip_runtime.h>
#include <math.h>

// Problem constants (match reference)
#define NB   64     // num_groups (B)
#define NG   32     // group_size (G)
#define ND   2000   // output dim D
#define NM   16     // m_samples
#define NE   16     // noise dim
#define NDIN 256
#define NK   272    // DIN + E
#define DPAD 2048   // padded D for IPF

__device__ __forceinline__ float clampf(float v, float lo, float hi) {
    return fminf(fmaxf(v, lo), hi);
}

__device__ __forceinline__ float softplusf(float v) {
    // jax.nn.softplus: stable log1p(exp(x)); inputs here are in ~[-3,3]
    return (v > 20.f) ? v : log1pf(expf(v));
}

// ---------------------------------------------------------------------------
// K2: loss.  One block per b.  Uses linearity: pred[b,m] = xs_b@Wx + ns_{b,m}@We + G*bias.
// Stages pred[16][chunk] in LDS, then 152 reduction tasks (16 conf + 136 pairs incl diag).
// ---------------------------------------------------------------------------
extern "C" __global__ __launch_bounds__(256)
void k2_loss(const float* __restrict__ x, const float* __restrict__ nl,
             const float* __restrict__ tgt, const float* __restrict__ W,
             const float* __restrict__ bias, float* __restrict__ out) {
    const int b = blockIdx.x, t = threadIdx.x;
    __shared__ float xsl[NDIN];        // sum over g of x rows
    __shared__ float nsl[NM * NE];     // sum over g of noise rows
    __shared__ float tg[256];
    __shared__ float pt[NM][260];      // pred chunk, stride 260 (16B-aligned rows)
    __shared__ float res[152];

    // g-sums (fused former K1)
    {
        const float* xb = x + (size_t)b * NG * NDIN;
        float s = 0.f;
        for (int g = 0; g < NG; ++g) s += xb[g * NDIN + t];
        xsl[t] = s;
        const float* nb = nl + (size_t)b * NG * (NM * NE);
        float s2 = 0.f;
        for (int g = 0; g < NG; ++g) s2 += nb[g * (NM * NE) + t];
        nsl[t] = s2;
    }

    // task mapping for pair tasks: t in [16,152) -> (tm,tn), tm<=tn, stable order
    int tm = 0, tn = 0;
    if (t >= 16 && t < 152) {
        int p = t - 16;
        for (int m = 0; m < NM; ++m) {
            int c = NM - m;
            if (p < c) { tm = m; tn = m + p; break; }
            p -= c;
        }
    }

    float acc = 0.f;
    for (int c0 = 0; c0 < ND; c0 += 256) {
        const int clen = min(256, ND - c0);   // 256 or 208, both %4==0
        __syncthreads();                       // protect pt/tg (and xsl/nsl on first pass)
        if (t < clen) {
            const int d = c0 + t;
            tg[t] = tgt[b * ND + d];
            float xw = 0.f;
            #pragma unroll 8
            for (int k = 0; k < NDIN; ++k) xw += xsl[k] * W[k * ND + d];
            float we[NE];
            #pragma unroll
            for (int e = 0; e < NE; ++e) we[e] = W[(NDIN + e) * ND + d];
            const float base0 = xw + (float)NG * bias[d];
            #pragma unroll
            for (int m = 0; m < NM; ++m) {
                float pm = base0;
                #pragma unroll
                for (int e = 0; e < NE; ++e) pm += nsl[m * NE + e] * we[e];
                pt[m][t] = pm;
            }
        }
        __syncthreads();
        if (t < 16) {
            const float4* pa  = (const float4*)&pt[t][0];
            const float4* tga = (const float4*)&tg[0];
            float a = 0.f;
            for (int i = 0; i < clen / 4; ++i) {
                float4 pv = pa[i], tv = tga[i];
                float e0 = pv.x - tv.x, e1 = pv.y - tv.y, e2 = pv.z - tv.z, e3 = pv.w - tv.w;
                a += e0 * e0 + e1 * e1 + e2 * e2 + e3 * e3;
            }
            acc += a;
        } else if (t < 152) {
            const float4* pa = (const float4*)&pt[tm][0];
            const float4* pb = (const float4*)&pt[tn][0];
            float a = 0.f;
            for (int i = 0; i < clen / 4; ++i) {
                float4 u = pa[i], v = pb[i];
                a += u.x * v.x + u.y * v.y + u.z * v.z + u.w * v.w;
            }
            acc += a;
        }
    }
    __syncthreads();
    if (t < 152) res[t] = acc;
    __syncthreads();
    if (t == 0) {
        float conf = 0.f;
        for (int m = 0; m < NM; ++m) conf += sqrtf(res[m]);
        conf *= (1.f / NM);
        float pd = 0.f;
        for (int m = 0; m < NM; ++m) {
            const int offm = 16 + m * NM - m * (m - 1) / 2;
            const float sqm = res[offm];
            for (int n = m + 1; n < NM; ++n) {
                const int offn = 16 + n * NM - n * (n - 1) / 2;
                const float sqn = res[offn];
                const float inn = res[offm + (n - m)];
                pd += sqrtf(fmaxf(sqm + sqn - 2.f * inn, 1e-6f));
            }
        }
        pd = 2.f * pd / (float)(NM * (NM - 1));   // sum over m!=n / (M(M-1))
        atomicAdd(out, (conf - 0.5f * pd) * (1.f / NB));
    }
}

// ---------------------------------------------------------------------------
// K3: x_pred = softplus(concat(x, noise_sample) @ W + bias)  -> ws (2048 x 2000)
// 256 blocks x 256 threads; block = 8 rows, thread = 4 consecutive d (x2 halves).
// ---------------------------------------------------------------------------
extern "C" __global__ __launch_bounds__(256)
void k3_xpred(const float* __restrict__ x, const float* __restrict__ nsamp,
              const float* __restrict__ W, const float* __restrict__ bias,
              float* __restrict__ xp) {
    const int rb = blockIdx.x, t = threadIdx.x;
    __shared__ float xr[8][NK];
    #pragma unroll
    for (int r = 0; r < 8; ++r) {
        const int row = rb * 8 + r;
        xr[r][t] = x[(size_t)row * NDIN + t];
        if (t < NE) xr[r][NDIN + t] = nsamp[row * NE + t];
    }
    __syncthreads();
    for (int h = 0; h < 2; ++h) {
        const int d = h * 1024 + t * 4;
        if (d >= ND) break;    // only h=1, t>=244; no barriers below
        float acc[8][4];
        #pragma unroll
        for (int r = 0; r < 8; ++r) {
            acc[r][0] = acc[r][1] = acc[r][2] = acc[r][3] = 0.f;
        }
        for (int k = 0; k < NK; k += 4) {
            float4 w[4];
            #pragma unroll
            for (int kk = 0; kk < 4; ++kk) w[kk] = *(const float4*)&W[(size_t)(k + kk) * ND + d];
            #pragma unroll
            for (int r = 0; r < 8; ++r) {
                const float4 xv = *(const float4*)&xr[r][k];
                const float xa0 = xv.x, xa1 = xv.y, xa2 = xv.z, xa3 = xv.w;
                acc[r][0] += xa0 * w[0].x + xa1 * w[1].x + xa2 * w[2].x + xa3 * w[3].x;
                acc[r][1] += xa0 * w[0].y + xa1 * w[1].y + xa2 * w[2].y + xa3 * w[3].y;
                acc[r][2] += xa0 * w[0].z + xa1 * w[1].z + xa2 * w[2].z + xa3 * w[3].z;
                acc[r][3] += xa0 * w[0].w + xa1 * w[1].w + xa2 * w[2].w + xa3 * w[3].w;
            }
        }
        const float4 bv = *(const float4*)&bias[d];
        #pragma unroll
        for (int r = 0; r < 8; ++r) {
            float4 o;
            o.x = softplusf(acc[r][0] + bv.x);
            o.y = softplusf(acc[r][1] + bv.y);
            o.z = softplusf(acc[r][2] + bv.z);
            o.w = softplusf(acc[r][3] + bv.w);
            *(float4*)&xp[(size_t)(rb * 8 + r) * ND + d] = o;
        }
    }
}

// ---------------------------------------------------------------------------
// K4: IPF, one block per b, 1024 threads, y0 register-resident (8g x 8d per thread).
// Factorized: y_k = y0 * A[d] * B[g].  60 iterations.  Writes z = y0*A*B back
// into xp IN PLACE (no extra workspace needed).
// Smoothing skipped: softplus>0 => col sums>0; row smoothing provably dead.
// ---------------------------------------------------------------------------
extern "C" __global__ __launch_bounds__(1024)
void k4_ipf(float* __restrict__ xp, const int* __restrict__ tsum) {
    const int b = blockIdx.x, t = threadIdx.x;
    const int gb = t >> 8;        // 0..3 (block of 8 g)
    const int db = t & 255;       // 0..255 (block of 8 d)
    const int d0 = db * 8;

    __shared__ float Al[DPAD];              // 8 KB  master column factors
    __shared__ float Bl[NG];                // master row factors
    __shared__ float Rl[NG];                // row anchors
    __shared__ float scratch[256 * 33];     // 33 KB union: colp[4][2048] / rowp[256][33] / ztile[32][257]
    __shared__ float rowp2[16][33];         // 2 KB second-level row partials

    // --- load y0 (clip >= 0) ---
    float y0[8][8];
    #pragma unroll
    for (int gi = 0; gi < 8; ++gi) {
        const int row = b * NG + gb * 8 + gi;
        const float* base = xp + (size_t)row * ND;
        if (db < 250) {
            const float4 v0 = *(const float4*)(base + d0);
            const float4 v1 = *(const float4*)(base + d0 + 4);
            y0[gi][0] = fmaxf(v0.x, 0.f); y0[gi][1] = fmaxf(v0.y, 0.f);
            y0[gi][2] = fmaxf(v0.z, 0.f); y0[gi][3] = fmaxf(v0.w, 0.f);
            y0[gi][4] = fmaxf(v1.x, 0.f); y0[gi][5] = fmaxf(v1.y, 0.f);
            y0[gi][6] = fmaxf(v1.z, 0.f); y0[gi][7] = fmaxf(v1.w, 0.f);
        } else {
            #pragma unroll
            for (int di = 0; di < 8; ++di) y0[gi][di] = 0.f;
        }
    }
    // C for the two d's this thread owns in phase P2 (d = t, t+1024)
    float Cr[2];
    Cr[0] = (float)tsum[b * ND + t];                                   // t < 1024 < 2000
    Cr[1] = (t + 1024 < ND) ? (float)tsum[b * ND + t + 1024] : 0.f;
    Al[t] = 1.f; Al[t + 1024] = 1.f;
    if (t < NG) Bl[t] = 1.f;

    // --- row anchors R[g] = sum_d y0 ---
    #pragma unroll
    for (int gi = 0; gi < 8; ++gi) {
        float s = 0.f;
        #pragma unroll
        for (int di = 0; di < 8; ++di) s += y0[gi][di];
        scratch[db * 33 + gb * 8 + gi] = s;
    }
    __syncthreads();
    if (t < 512) {
        const int g = t & 31, c = t >> 5;
        float s = 0.f;
        #pragma unroll
        for (int j = 0; j < 16; ++j) s += scratch[(c * 16 + j) * 33 + g];
        rowp2[c][g] = s;
    }
    __syncthreads();
    if (t < NG) {
        float s = 0.f;
        #pragma unroll
        for (int c = 0; c < 16; ++c) s += rowp2[c][t];
        Rl[t] = s;
    }
    __syncthreads();

    // --- 60 IPF iterations ---
    for (int it = 0; it < 60; ++it) {
        // P1: column partials  cp[d] = sum_gi y0 * B
        float B8[8];
        #pragma unroll
        for (int gi = 0; gi < 8; ++gi) B8[gi] = Bl[gb * 8 + gi];
        float cp[8];
        #pragma unroll
        for (int di = 0; di < 8; ++di) {
            float s = 0.f;
            #pragma unroll
            for (int gi = 0; gi < 8; ++gi) s += y0[gi][di] * B8[gi];
            cp[di] = s;
        }
        float4* cw = (float4*)&scratch[gb * DPAD + d0];
        cw[0] = make_float4(cp[0], cp[1], cp[2], cp[3]);
        cw[1] = make_float4(cp[4], cp[5], cp[6], cp[7]);
        __syncthreads();
        // P2: col totals -> ratio -> update A
        #pragma unroll
        for (int j = 0; j < 2; ++j) {
            const int d = t + j * 1024;
            const float s = scratch[d] + scratch[DPAD + d] + scratch[2 * DPAD + d] + scratch[3 * DPAD + d];
            const float a = Al[d];
            const float colv = fmaxf(a * s, 1e-12f);
            const float r = clampf(Cr[j] / colv, 0.75f, 1.25f);
            Al[d] = a * r;
        }
        __syncthreads();
        // P3: row partials  rp[g] = sum_di y0 * A
        const float4 a0 = *(const float4*)&Al[d0];
        const float4 a1 = *(const float4*)&Al[d0 + 4];
        const float A8[8] = {a0.x, a0.y, a0.z, a0.w, a1.x, a1.y, a1.z, a1.w};
        #pragma unroll
        for (int gi = 0; gi < 8; ++gi) {
            float s = 0.f;
            #pragma unroll
            for (int di = 0; di < 8; ++di) s += y0[gi][di] * A8[di];
            scratch[db * 33 + gb * 8 + gi] = s;
        }
        __syncthreads();
        // P4: reduce 256 -> 16 per g
        if (t < 512) {
            const int g = t & 31, c = t >> 5;
            float s = 0.f;
            #pragma unroll
            for (int j = 0; j < 16; ++j) s += scratch[(c * 16 + j) * 33 + g];
            rowp2[c][g] = s;
        }
        __syncthreads();
        // P5: row totals -> ratio -> update B
        if (t < NG) {
            float s = 0.f;
            #pragma unroll
            for (int c = 0; c < 16; ++c) s += rowp2[c][t];
            const float Bg = Bl[t];
            const float row = fmaxf(Bg * s, 1e-12f);
            const float r = clampf(Rl[t] / row, 0.75f, 1.25f);
            Bl[t] = Bg * r;
        }
        __syncthreads();
    }

    // --- write z = y0 * A * B back into xp in place ---
    const float4 fa0 = *(const float4*)&Al[d0];
    const float4 fa1 = *(const float4*)&Al[d0 + 4];
    const float A8f[8] = {fa0.x, fa0.y, fa0.z, fa0.w, fa1.x, fa1.y, fa1.z, fa1.w};
    if (db < 250) {
        #pragma unroll
        for (int gi = 0; gi < 8; ++gi) {
            const int row = b * NG + gb * 8 + gi;
            const float bg = Bl[gb * 8 + gi];
            float4 z0, z1;
            z0.x = y0[gi][0] * A8f[0] * bg; z0.y = y0[gi][1] * A8f[1] * bg;
            z0.z = y0[gi][2] * A8f[2] * bg; z0.w = y0[gi][3] * A8f[3] * bg;
            z1.x = y0[gi][4] * A8f[4] * bg; z1.y = y0[gi][5] * A8f[5] * bg;
            z1.z = y0[gi][6] * A8f[6] * bg; z1.w = y0[gi][7] * A8f[7] * bg;
            *(float4*)&xp[(size_t)row * ND + d0]     = z0;
            *(float4*)&xp[(size_t)row * ND + d0 + 4] = z1;
        }
    }
}

// ---------------------------------------------------------------------------
// K5: final column scale (C/col) + exact integerization.  One half-wave (32
// lanes = 32 g) per d; 64 d per block; grid (32, 64).
// ---------------------------------------------------------------------------
extern "C" __global__ __launch_bounds__(256)
void k5_round(const float* __restrict__ xp, const int* __restrict__ tsum,
              float* __restrict__ out) {
    const int b  = blockIdx.y;
    const int d0 = blockIdx.x * 64;
    const int t  = threadIdx.x;
    __shared__ float ylds[NG][65];

    // coalesced tile load (32 g x 64 d), transposed access later via LDS
    #pragma unroll
    for (int i = 0; i < 8; ++i) {
        const int idx = t + i * 256;
        const int g = idx >> 6, dd = idx & 63;
        const int d = d0 + dd;
        ylds[g][dd] = (d < ND) ? xp[(size_t)(b * NG + g) * ND + d] : 0.f;
    }
    __syncthreads();

    const int lane = t & 31;   // g
    const int half = t >> 5;   // 0..7
    for (int s = 0; s < 8; ++s) {
        const int dd = half * 8 + s;
        const int d  = d0 + dd;
        const float z = ylds[lane][dd];
        float ssum = z;
        #pragma unroll
        for (int o = 1; o < 32; o <<= 1) ssum += __shfl_xor(ssum, o, 32);
        const int Ci = (d < ND) ? tsum[b * ND + d] : 0;
        const float F = (float)Ci / fmaxf(ssum, 1e-12f);   // final y *= C/col
        const float y = z * F;
        const float fl = floorf(y);
        const float frac = y - fl;
        int yv = (int)fl;
        int isum = yv;
        #pragma unroll
        for (int o = 1; o < 32; o <<= 1) isum += __shfl_xor(isum, o, 32);
        const int need = Ci - isum;
        const int pos = max(need, 0);
        const int q = pos >> 5;            // pos // G
        yv += q;
        const int r = pos - (q << 5);
        if (r > 0) {
            int rank = 0;                   // stable rank of -frac (descending)
            for (int j = 0; j < 32; ++j) {
                const float fj = __shfl(frac, j, 32);
                rank += (fj > frac || (fj == frac && j < lane)) ? 1 : 0;
            }
            if (rank < r) yv += 1;
        }
        // negative-residual branch (provably inert for this data, kept for fidelity)
        int tot = yv;
        #pragma unroll
        for (int o = 1; o < 32; o <<= 1) tot += __shfl_xor(tot, o, 32);
        const int need2 = Ci - tot;
        int neg = max(-need2, 0);
        neg = min(neg, tot);
        if (neg > 0) {
            const int q2 = neg >> 5;
            const int before = yv;
            yv = max(yv - q2, 0);
            int rem = before - yv;
            #pragma unroll
            for (int o = 1; o < 32; o <<= 1) rem += __shfl_xor(rem, o, 32);
            const int r2 = neg - rem;
            if (r2 > 0) {
                const float fm = (yv > 0) ? frac : __builtin_inff();
                int rank2 = 0;              // stable rank ascending
                for (int j = 0; j < 32; ++j) {
                    const float fj = __shfl(fm, j, 32);
                    rank2 += (fj < fm || (fj == fm && j < lane)) ? 1 : 0;
                }
                if (rank2 < r2) yv -= 1;
            }
            yv = max(yv, 0);
        }
        ylds[lane][dd] = (float)yv;
    }
    __syncthreads();
    // coalesced store
    #pragma unroll
    for (int i = 0; i < 8; ++i) {
        const int idx = t + i * 256;
        const int g = idx >> 6, dd = idx & 63;
        const int d = d0 + dd;
        if (d < ND) out[1 + (size_t)(b * NG + g) * ND + d] = ylds[g][dd];
    }
}

// ---------------------------------------------------------------------------
extern "C" void kernel_launch(void* const* d_in, const int* in_sizes, int n_in,
                              void* d_out, int out_size, void* d_ws, size_t ws_size,
                              hipStream_t stream) {
    const float* x     = (const float*)d_in[0];   // (2048, 256)
    const float* tgt   = (const float*)d_in[1];   // (64, 2000)
    const int*   tsum  = (const int*)d_in[2];     // (64, 2000) int32
    const float* W     = (const float*)d_in[3];   // (272, 2000)
    const float* bias  = (const float*)d_in[4];   // (2000,)
    const float* nl    = (const float*)d_in[5];   // (32768, 16)
    const float* nsamp = (const float*)d_in[6];   // (2048, 16)
    float* out = (float*)d_out;                   // [loss(1)] + [y_int as float (4096000)]
    float* xp  = (float*)d_ws;                    // 2048*2000 floats = 16,384,000 B

    (void)in_sizes; (void)n_in; (void)out_size; (void)ws_size;

    // out[0] accumulates the loss via atomicAdd
    hipMemsetAsync(d_out, 0, sizeof(float), stream);

    hipLaunchKernelGGL(k3_xpred, dim3(256), dim3(256), 0, stream, x, nsamp, W, bias, xp);
    hipLaunchKernelGGL(k2_loss,  dim3(NB),  dim3(256), 0, stream, x, nl, tgt, W, bias, out);
    hipLaunchKernelGGL(k4_ipf,   dim3(NB),  dim3(1024), 0, stream, xp, tsum);
    hipLaunchKernelGGL(k5_round, dim3(32, NB), dim3(256), 0, stream, xp, tsum, out);
}

// Round 2
// 504.592 us; speedup vs baseline: 1.3654x; 1.3654x over previous
//
#include <hip/hip_runtime.h>
#include <math.h>

// Problem constants (match reference)
#define NB   64     // num_groups (B)
#define NG   32     // group_size (G)
#define ND   2000   // output dim D
#define NM   16     // m_samples
#define NE   16     // noise dim
#define NDIN 256
#define NK   272    // DIN + E

__device__ __forceinline__ float clampf(float v, float lo, float hi) {
    return fminf(fmaxf(v, lo), hi);
}

__device__ __forceinline__ float softplusf(float v) {
    return (v > 20.f) ? v : log1pf(expf(v));
}

// Packed butterfly: reduce v[0..31] (per-g partials) over 64 lanes.
// Result: v[0] holds the full-wave total for g = lane&31 (dup on lane&32).
__device__ __forceinline__ void wave_reduce32(float v[NG], int lane) {
    #pragma unroll
    for (int g = 0; g < NG; ++g) v[g] += __shfl_xor(v[g], 32);
    {
        const bool hi = (lane & 16) != 0;
        #pragma unroll
        for (int k = 0; k < 16; ++k) {
            float send = hi ? v[k] : v[k + 16];
            float recv = __shfl_xor(send, 16);
            v[k] = (hi ? v[k + 16] : v[k]) + recv;
        }
    }
    {
        const bool hi = (lane & 8) != 0;
        #pragma unroll
        for (int k = 0; k < 8; ++k) {
            float send = hi ? v[k] : v[k + 8];
            float recv = __shfl_xor(send, 8);
            v[k] = (hi ? v[k + 8] : v[k]) + recv;
        }
    }
    {
        const bool hi = (lane & 4) != 0;
        #pragma unroll
        for (int k = 0; k < 4; ++k) {
            float send = hi ? v[k] : v[k + 4];
            float recv = __shfl_xor(send, 4);
            v[k] = (hi ? v[k + 4] : v[k]) + recv;
        }
    }
    {
        const bool hi = (lane & 2) != 0;
        #pragma unroll
        for (int k = 0; k < 2; ++k) {
            float send = hi ? v[k] : v[k + 2];
            float recv = __shfl_xor(send, 2);
            v[k] = (hi ? v[k + 2] : v[k]) + recv;
        }
    }
    {
        const bool hi = (lane & 1) != 0;
        float send = hi ? v[0] : v[1];
        float recv = __shfl_xor(send, 1);
        v[0] = (hi ? v[1] : v[0]) + recv;
    }
}

// ---------------------------------------------------------------------------
// K2: loss.  One block per b.  Uses linearity: pred[b,m] = xs_b@Wx + ns_{b,m}@We + G*bias.
// ---------------------------------------------------------------------------
extern "C" __global__ __launch_bounds__(256)
void k2_loss(const float* __restrict__ x, const float* __restrict__ nl,
             const float* __restrict__ tgt, const float* __restrict__ W,
             const float* __restrict__ bias, float* __restrict__ out) {
    const int b = blockIdx.x, t = threadIdx.x;
    __shared__ float xsl[NDIN];
    __shared__ float nsl[NM * NE];
    __shared__ float tg[256];
    __shared__ float pt[NM][260];
    __shared__ float res[152];

    {
        const float* xb = x + (size_t)b * NG * NDIN;
        float s = 0.f;
        for (int g = 0; g < NG; ++g) s += xb[g * NDIN + t];
        xsl[t] = s;
        const float* nb = nl + (size_t)b * NG * (NM * NE);
        float s2 = 0.f;
        for (int g = 0; g < NG; ++g) s2 += nb[g * (NM * NE) + t];
        nsl[t] = s2;
    }

    int tm = 0, tn = 0;
    if (t >= 16 && t < 152) {
        int p = t - 16;
        for (int m = 0; m < NM; ++m) {
            int c = NM - m;
            if (p < c) { tm = m; tn = m + p; break; }
            p -= c;
        }
    }

    float acc = 0.f;
    for (int c0 = 0; c0 < ND; c0 += 256) {
        const int clen = min(256, ND - c0);
        __syncthreads();
        if (t < clen) {
            const int d = c0 + t;
            tg[t] = tgt[b * ND + d];
            float xw = 0.f;
            #pragma unroll 8
            for (int k = 0; k < NDIN; ++k) xw += xsl[k] * W[k * ND + d];
            float we[NE];
            #pragma unroll
            for (int e = 0; e < NE; ++e) we[e] = W[(NDIN + e) * ND + d];
            const float base0 = xw + (float)NG * bias[d];
            #pragma unroll
            for (int m = 0; m < NM; ++m) {
                float pm = base0;
                #pragma unroll
                for (int e = 0; e < NE; ++e) pm += nsl[m * NE + e] * we[e];
                pt[m][t] = pm;
            }
        }
        __syncthreads();
        if (t < 16) {
            const float4* pa  = (const float4*)&pt[t][0];
            const float4* tga = (const float4*)&tg[0];
            float a = 0.f;
            for (int i = 0; i < clen / 4; ++i) {
                float4 pv = pa[i], tv = tga[i];
                float e0 = pv.x - tv.x, e1 = pv.y - tv.y, e2 = pv.z - tv.z, e3 = pv.w - tv.w;
                a += e0 * e0 + e1 * e1 + e2 * e2 + e3 * e3;
            }
            acc += a;
        } else if (t < 152) {
            const float4* pa = (const float4*)&pt[tm][0];
            const float4* pb = (const float4*)&pt[tn][0];
            float a = 0.f;
            for (int i = 0; i < clen / 4; ++i) {
                float4 u = pa[i], v = pb[i];
                a += u.x * v.x + u.y * v.y + u.z * v.z + u.w * v.w;
            }
            acc += a;
        }
    }
    __syncthreads();
    if (t < 152) res[t] = acc;
    __syncthreads();
    if (t == 0) {
        float conf = 0.f;
        for (int m = 0; m < NM; ++m) conf += sqrtf(res[m]);
        conf *= (1.f / NM);
        float pd = 0.f;
        for (int m = 0; m < NM; ++m) {
            const int offm = 16 + m * NM - m * (m - 1) / 2;
            const float sqm = res[offm];
            for (int n = m + 1; n < NM; ++n) {
                const int offn = 16 + n * NM - n * (n - 1) / 2;
                const float sqn = res[offn];
                const float inn = res[offm + (n - m)];
                pd += sqrtf(fmaxf(sqm + sqn - 2.f * inn, 1e-6f));
            }
        }
        pd = 2.f * pd / (float)(NM * (NM - 1));
        atomicAdd(out, (conf - 0.5f * pd) * (1.f / NB));
    }
}

// ---------------------------------------------------------------------------
// K3: x_pred = softplus(concat(x, noise_sample) @ W + bias)  -> ws (2048 x 2000)
// ---------------------------------------------------------------------------
extern "C" __global__ __launch_bounds__(256)
void k3_xpred(const float* __restrict__ x, const float* __restrict__ nsamp,
              const float* __restrict__ W, const float* __restrict__ bias,
              float* __restrict__ xp) {
    const int rb = blockIdx.x, t = threadIdx.x;
    __shared__ float xr[8][NK];
    #pragma unroll
    for (int r = 0; r < 8; ++r) {
        const int row = rb * 8 + r;
        xr[r][t] = x[(size_t)row * NDIN + t];
        if (t < NE) xr[r][NDIN + t] = nsamp[row * NE + t];
    }
    __syncthreads();
    for (int h = 0; h < 2; ++h) {
        const int d = h * 1024 + t * 4;
        if (d >= ND) break;
        float acc[8][4];
        #pragma unroll
        for (int r = 0; r < 8; ++r) {
            acc[r][0] = acc[r][1] = acc[r][2] = acc[r][3] = 0.f;
        }
        for (int k = 0; k < NK; k += 4) {
            float4 w[4];
            #pragma unroll
            for (int kk = 0; kk < 4; ++kk) w[kk] = *(const float4*)&W[(size_t)(k + kk) * ND + d];
            #pragma unroll
            for (int r = 0; r < 8; ++r) {
                const float4 xv = *(const float4*)&xr[r][k];
                const float xa0 = xv.x, xa1 = xv.y, xa2 = xv.z, xa3 = xv.w;
                acc[r][0] += xa0 * w[0].x + xa1 * w[1].x + xa2 * w[2].x + xa3 * w[3].x;
                acc[r][1] += xa0 * w[0].y + xa1 * w[1].y + xa2 * w[2].y + xa3 * w[3].y;
                acc[r][2] += xa0 * w[0].z + xa1 * w[1].z + xa2 * w[2].z + xa3 * w[3].z;
                acc[r][3] += xa0 * w[0].w + xa1 * w[1].w + xa2 * w[2].w + xa3 * w[3].w;
            }
        }
        const float4 bv = *(const float4*)&bias[d];
        #pragma unroll
        for (int r = 0; r < 8; ++r) {
            float4 o;
            o.x = softplusf(acc[r][0] + bv.x);
            o.y = softplusf(acc[r][1] + bv.y);
            o.z = softplusf(acc[r][2] + bv.z);
            o.w = softplusf(acc[r][3] + bv.w);
            *(float4*)&xp[(size_t)(rb * 8 + r) * ND + d] = o;
        }
    }
}

// ---------------------------------------------------------------------------
// K4: IPF + final scale + exact integerization, fused.  One block per b,
// 512 threads; thread t owns d = 4t..4t+3 FULL-COLUMN (all 32 g) in registers.
// Column update is thread-local (no barrier); row update = in-register
// butterfly + one 8x32 LDS stage => 2 barriers/iter (was 5, with 44.5 KB LDS).
// Epilogue: y = y0*A*B*C/col, floor/frac, stable rank over 32 fracs
// thread-locally; writes integer result straight to out (no z round-trip).
// ---------------------------------------------------------------------------
extern "C" __global__ __launch_bounds__(512)
void k4_ipf_round(const float* __restrict__ xp, const int* __restrict__ tsum,
                  float* __restrict__ out) {
    const int b = blockIdx.x, t = threadIdx.x;
    const int lane = t & 63;
    const int w = t >> 6;                 // wave 0..7
    const int d0 = t * 4;
    const bool valid = (d0 < ND);         // t < 500

    __shared__ __align__(16) float Bl[NG];
    __shared__ float Rl[NG];
    __shared__ float wred[8][NG + 1];

    // ---- load y0 = max(x_pred, 0): y0r[j][g] for d = d0+j ----
    float y0r[4][NG];
    #pragma unroll
    for (int g = 0; g < NG; ++g) {
        float4 v = make_float4(0.f, 0.f, 0.f, 0.f);
        if (valid) v = *(const float4*)(xp + (size_t)(b * NG + g) * ND + d0);
        y0r[0][g] = fmaxf(v.x, 0.f);
        y0r[1][g] = fmaxf(v.y, 0.f);
        y0r[2][g] = fmaxf(v.z, 0.f);
        y0r[3][g] = fmaxf(v.w, 0.f);
    }
    float Cc[4] = {0.f, 0.f, 0.f, 0.f};
    if (valid) {
        const int4 ci = *(const int4*)(tsum + (size_t)b * ND + d0);
        Cc[0] = (float)ci.x; Cc[1] = (float)ci.y; Cc[2] = (float)ci.z; Cc[3] = (float)ci.w;
    }
    float Ac[4] = {1.f, 1.f, 1.f, 1.f};
    if (t < NG) Bl[t] = 1.f;

    // ---- row anchors R[g] = sum_d y0 ----
    {
        float v[NG];
        #pragma unroll
        for (int g = 0; g < NG; ++g)
            v[g] = y0r[0][g] + y0r[1][g] + y0r[2][g] + y0r[3][g];
        wave_reduce32(v, lane);
        if (lane < NG) wred[w][lane] = v[0];
        __syncthreads();
        if (t < NG) {
            float s = 0.f;
            #pragma unroll
            for (int w2 = 0; w2 < 8; ++w2) s += wred[w2][t];
            Rl[t] = s;
        }
        __syncthreads();
    }

    // ---- 60 IPF iterations ----
    for (int it = 0; it < 60; ++it) {
        // cache B (broadcast b128 LDS reads)
        float Bg[NG];
        #pragma unroll
        for (int g = 0; g < NG; g += 4) {
            const float4 bv = *(const float4*)&Bl[g];
            Bg[g] = bv.x; Bg[g + 1] = bv.y; Bg[g + 2] = bv.z; Bg[g + 3] = bv.w;
        }
        // column phase: thread-local
        float s0 = 0.f, s1 = 0.f, s2 = 0.f, s3 = 0.f;
        #pragma unroll
        for (int g = 0; g < NG; ++g) {
            const float bg = Bg[g];
            s0 += y0r[0][g] * bg; s1 += y0r[1][g] * bg;
            s2 += y0r[2][g] * bg; s3 += y0r[3][g] * bg;
        }
        float sj[4] = {s0, s1, s2, s3};
        #pragma unroll
        for (int j = 0; j < 4; ++j) {
            const float colv = fmaxf(Ac[j] * sj[j], 1e-12f);
            const float r = clampf(Cc[j] / colv, 0.75f, 1.25f);
            Ac[j] *= r;
        }
        // row phase: partials + butterfly + 8x32 LDS reduce
        float v[NG];
        #pragma unroll
        for (int g = 0; g < NG; ++g)
            v[g] = y0r[0][g] * Ac[0] + y0r[1][g] * Ac[1]
                 + y0r[2][g] * Ac[2] + y0r[3][g] * Ac[3];
        wave_reduce32(v, lane);
        if (lane < NG) wred[w][lane] = v[0];
        __syncthreads();
        if (t < NG) {
            float ssum = 0.f;
            #pragma unroll
            for (int w2 = 0; w2 < 8; ++w2) ssum += wred[w2][t];
            const float Bgc = Bl[t];
            const float rown = fmaxf(Bgc * ssum, 1e-12f);
            const float rr = clampf(Rl[t] / rown, 0.75f, 1.25f);
            Bl[t] = Bgc * rr;
        }
        __syncthreads();
    }

    // ---- epilogue: final scale + integerization, thread-local per d ----
    if (!valid) return;
    #pragma unroll
    for (int j = 0; j < 4; ++j) {
        float fr[NG];
        int   yv[NG];
        // z = y0*A*B ; col sum ; F = C/col
        float s = 0.f;
        #pragma unroll
        for (int g = 0; g < NG; ++g) {
            const float z = y0r[j][g] * Ac[j] * Bl[g];
            fr[g] = z;
            s += z;
        }
        const float F = Cc[j] / fmaxf(s, 1e-12f);
        int isum = 0;
        #pragma unroll
        for (int g = 0; g < NG; ++g) {
            const float y = fr[g] * F;
            const float fl = floorf(y);
            yv[g] = (int)fl;
            fr[g] = y - fl;
            isum += yv[g];
        }
        const int Ci = (int)Cc[j];
        const int need = Ci - isum;
        const int pos = max(need, 0);
        const int q = pos >> 5;
        const int r = pos & 31;
        #pragma unroll
        for (int g = 0; g < NG; ++g) yv[g] += q;
        // stable descending rank; +1 to the r largest fracs
        #pragma unroll
        for (int g = 0; g < NG; ++g) {
            int rank = 0;
            #pragma unroll
            for (int h = 0; h < NG; ++h) {
                if (h == g) continue;
                rank += (h < g) ? (fr[h] >= fr[g] ? 1 : 0) : (fr[h] > fr[g] ? 1 : 0);
            }
            if (rank < r) yv[g] += 1;
        }
        // negative residual (need<0 => pos=0): remove from smallest fracs among yv>0
        int neg = max(-need, 0);
        neg = min(neg, isum + pos);
        if (neg > 0) {
            const int q2 = neg >> 5;
            int removed = 0;
            unsigned elig = 0u;
            #pragma unroll
            for (int g = 0; g < NG; ++g) {
                const int yb = yv[g];
                const int yn = max(yb - q2, 0);
                removed += yb - yn;
                yv[g] = yn;
                if (yn > 0) elig |= (1u << g);
            }
            int r2 = neg - removed;
            for (; r2 > 0; --r2) {
                float best = __builtin_inff();
                int bi = -1;
                #pragma unroll
                for (int g = 0; g < NG; ++g) {
                    const float fm = ((elig >> g) & 1u) ? fr[g] : __builtin_inff();
                    if (fm < best) { best = fm; bi = g; }
                }
                if (bi < 0) break;
                elig &= ~(1u << bi);
                yv[bi] = max(yv[bi] - 1, 0);
            }
        }
        // store this d-column (scalar dword stores; L2 write-combines)
        const size_t ob = 1 + (size_t)(b * NG) * ND + (size_t)(d0 + j);
        #pragma unroll
        for (int g = 0; g < NG; ++g)
            out[ob + (size_t)g * ND] = (float)yv[g];
    }
}

// ---------------------------------------------------------------------------
extern "C" void kernel_launch(void* const* d_in, const int* in_sizes, int n_in,
                              void* d_out, int out_size, void* d_ws, size_t ws_size,
                              hipStream_t stream) {
    const float* x     = (const float*)d_in[0];
    const float* tgt   = (const float*)d_in[1];
    const int*   tsum  = (const int*)d_in[2];
    const float* W     = (const float*)d_in[3];
    const float* bias  = (const float*)d_in[4];
    const float* nl    = (const float*)d_in[5];
    const float* nsamp = (const float*)d_in[6];
    float* out = (float*)d_out;
    float* xp  = (float*)d_ws;                  // 2048*2000 floats

    (void)in_sizes; (void)n_in; (void)out_size; (void)ws_size;

    hipMemsetAsync(d_out, 0, sizeof(float), stream);

    hipLaunchKernelGGL(k3_xpred,     dim3(256), dim3(256), 0, stream, x, nsamp, W, bias, xp);
    hipLaunchKernelGGL(k2_loss,      dim3(NB),  dim3(256), 0, stream, x, nl, tgt, W, bias, out);
    hipLaunchKernelGGL(k4_ipf_round, dim3(NB),  dim3(512), 0, stream, xp, tsum, out);
}